// Round 3
// baseline (369.869 us; speedup 1.0000x reference)
//
#include <hip/hip_runtime.h>

#define IDIM   256
#define HDIM   64
#define BATCH  1024
#define NITEMS 200
#define NCOLS  (IDIM * HDIM)   // 16384

typedef __bf16 bf16x8 __attribute__((ext_vector_type(8)));
typedef float  f32x4  __attribute__((ext_vector_type(4)));

__device__ __forceinline__ unsigned short f2bf(float f) {
    unsigned int u = __float_as_uint(f);
    u += 0x7FFFu + ((u >> 16) & 1u);   // round-to-nearest-even
    return (unsigned short)(u >> 16);
}

__device__ __forceinline__ bf16x8 cvt8(float4 f0, float4 f1) {
    bf16x8 r;
    r[0] = (__bf16)f0.x; r[1] = (__bf16)f0.y; r[2] = (__bf16)f0.z; r[3] = (__bf16)f0.w;
    r[4] = (__bf16)f1.x; r[5] = (__bf16)f1.y; r[6] = (__bf16)f1.z; r[7] = (__bf16)f1.w;
    return r;
}

// ---- W_q f32 (k=256 x n=16384) -> Bt bf16 [n][k] (transposed) ----
__global__ __launch_bounds__(256) void k_trans_wq(const float* __restrict__ Wq,
                                                  unsigned short* __restrict__ Bt) {
    __shared__ float tile[32][33];
    int n0 = blockIdx.x * 32;          // 512 n-tiles
    int k0 = blockIdx.y * 32;          // 8 k-tiles
    int tx = threadIdx.x & 31;
    int ty = threadIdx.x >> 5;         // 0..7
#pragma unroll
    for (int j = 0; j < 32; j += 8)
        tile[ty + j][tx] = Wq[(size_t)(k0 + ty + j) * NCOLS + n0 + tx];
    __syncthreads();
#pragma unroll
    for (int j = 0; j < 32; j += 8)
        Bt[(size_t)(n0 + ty + j) * IDIM + k0 + tx] = f2bf(tile[tx][ty + j]);
}

// ---- GEMM: P = query(1024x256 f32, cvt inline) @ Wq(256x16384 via Bt bf16),
//      fused bias+tanh+W_r reduce -> V[b][i] (1024x256 f32).
// One wave: 64(m) x 64(n) C tile. Explicit 2-stage register pipeline over K.
__global__ __launch_bounds__(256) void k_gemm_v(const float* __restrict__ Aq,
                                                const unsigned short* __restrict__ Bt,
                                                const float* __restrict__ bq,
                                                const float* __restrict__ Wr,
                                                float* __restrict__ V) {
    int w    = threadIdx.x >> 6;
    int lane = threadIdx.x & 63;
    int l16  = lane & 15;
    int quad = lane >> 4;
    int blk  = blockIdx.x;             // 1024 blocks
    int bn   = blk & 127;              // 128 n-blocks (each 2 n-tiles)
    int bm   = blk >> 7;               // 8 m-blocks  (each 2 m-tiles)
    int m_tile = bm * 2 + (w & 1);     // 0..15
    int n_tile = bn * 2 + (w >> 1);    // 0..255
    int m_base = m_tile * 64;
    int n_base = n_tile * 64;

    f32x4 acc[4][4] = {};
    const float*          Ap = Aq + (size_t)(m_base + l16) * IDIM + quad * 8;
    const unsigned short* Bp = Bt + (size_t)(n_base + l16) * IDIM + quad * 8;

    bf16x8 a_cur[4], b_cur[4];
#pragma unroll
    for (int t = 0; t < 4; t++) {
        float4 f0 = *(const float4*)(Ap + (size_t)t * 16 * IDIM);
        float4 f1 = *(const float4*)(Ap + (size_t)t * 16 * IDIM + 4);
        a_cur[t] = cvt8(f0, f1);
        b_cur[t] = *(const bf16x8*)(Bp + (size_t)t * 16 * IDIM);
    }

#pragma unroll 1
    for (int k0 = 0; k0 < IDIM; k0 += 32) {
        int k1 = k0 + 32;
        bf16x8 a_nxt[4], b_nxt[4];
        if (k1 < IDIM) {
#pragma unroll
            for (int t = 0; t < 4; t++) {
                float4 f0 = *(const float4*)(Ap + (size_t)t * 16 * IDIM + k1);
                float4 f1 = *(const float4*)(Ap + (size_t)t * 16 * IDIM + k1 + 4);
                a_nxt[t] = cvt8(f0, f1);
                b_nxt[t] = *(const bf16x8*)(Bp + (size_t)t * 16 * IDIM + k1);
            }
        }
#pragma unroll
        for (int mt = 0; mt < 4; mt++)
#pragma unroll
            for (int nt = 0; nt < 4; nt++)
                acc[mt][nt] = __builtin_amdgcn_mfma_f32_16x16x32_bf16(a_cur[mt], b_cur[nt], acc[mt][nt], 0, 0, 0);
        if (k1 < IDIM) {
#pragma unroll
            for (int t = 0; t < 4; t++) { a_cur[t] = a_nxt[t]; b_cur[t] = b_nxt[t]; }
        }
    }

    // epilogue: per lane, cols n_local = nt*16 + l16; h == n_local
    float bv[4], wr[4];
#pragma unroll
    for (int nt = 0; nt < 4; nt++) {
        int nl = nt * 16 + l16;
        bv[nt] = bq[n_base + nl];
        wr[nt] = Wr[nl];
    }
    int i = n_tile;
#pragma unroll
    for (int mt = 0; mt < 4; mt++) {
#pragma unroll
        for (int reg = 0; reg < 4; reg++) {
            float s = 0.0f;
#pragma unroll
            for (int nt = 0; nt < 4; nt++) {
                float c = acc[mt][nt][reg] + bv[nt];
                s += tanhf(c) * wr[nt];
            }
            s += __shfl_xor(s, 1);
            s += __shfl_xor(s, 2);
            s += __shfl_xor(s, 4);
            s += __shfl_xor(s, 8);
            if (l16 == 0) {
                int m = m_base + mt * 16 + quad * 4 + reg;   // D row = quad*4+reg
                V[m * IDIM + i] = s;
            }
        }
    }
}

// ---- fused score -> exp -> weighted accumulate, single pass over item ----
// one item per quad (16 lanes), 2 in flight per quad, 8 per wave.
__global__ __launch_bounds__(256) void k_score(const float* __restrict__ item,
                                               const float* __restrict__ V,
                                               float* __restrict__ out) {
    __shared__ float lacc[16][IDIM];   // 16 KB partials
    __shared__ float lS[16];
    int b    = blockIdx.x;
    int tid  = threadIdx.x;
    int wid  = tid >> 6;
    int lane = tid & 63;
    int l16  = lane & 15;
    int quad = lane >> 4;

    const float4* itemB = (const float4*)(item + (size_t)b * NITEMS * IDIM);
    const float4* Vb    = (const float4*)(V + (size_t)b * IDIM);

    float4 v[4];
#pragma unroll
    for (int c = 0; c < 4; c++) v[c] = Vb[l16 + 16 * c];

    float4 acc[4];
#pragma unroll
    for (int c = 0; c < 4; c++) acc[c] = make_float4(0.f, 0.f, 0.f, 0.f);
    float S = 0.f;

    for (int chunk = wid; chunk < 25; chunk += 4) {
        int r0 = chunk * 8 + quad;       // item for x0
        int r1 = r0 + 4;                 // item for x1 (max 199)
        float4 x0[4], x1[4];
#pragma unroll
        for (int c = 0; c < 4; c++) x0[c] = itemB[(size_t)r0 * 64 + l16 + 16 * c];
#pragma unroll
        for (int c = 0; c < 4; c++) x1[c] = itemB[(size_t)r1 * 64 + l16 + 16 * c];

        float d0 = 0.f, d1 = 0.f;
#pragma unroll
        for (int c = 0; c < 4; c++) {
            d0 += x0[c].x * v[c].x + x0[c].y * v[c].y + x0[c].z * v[c].z + x0[c].w * v[c].w;
            d1 += x1[c].x * v[c].x + x1[c].y * v[c].y + x1[c].z * v[c].z + x1[c].w * v[c].w;
        }
#pragma unroll
        for (int m = 1; m < 16; m <<= 1) {
            d0 += __shfl_xor(d0, m);
            d1 += __shfl_xor(d1, m);
        }
        float e0 = expf(d0);
        float e1 = expf(d1);
        S += e0 + e1;
#pragma unroll
        for (int c = 0; c < 4; c++) {
            acc[c].x += e0 * x0[c].x + e1 * x1[c].x;
            acc[c].y += e0 * x0[c].y + e1 * x1[c].y;
            acc[c].z += e0 * x0[c].z + e1 * x1[c].z;
            acc[c].w += e0 * x0[c].w + e1 * x1[c].w;
        }
    }

    int row = wid * 4 + quad;            // 16 partial rows
#pragma unroll
    for (int c = 0; c < 4; c++)
        ((float4*)&lacc[row][0])[l16 + 16 * c] = acc[c];
    if (l16 == 0) lS[row] = S;
    __syncthreads();

    float s = 0.f;
#pragma unroll
    for (int i = 0; i < 16; i++) s += lacc[i][tid];
    float Stot = 0.f;
#pragma unroll
    for (int i = 0; i < 16; i++) Stot += lS[i];
    out[(size_t)b * IDIM + tid] = s / (1.0f + Stot);
}

extern "C" void kernel_launch(void* const* d_in, const int* in_sizes, int n_in,
                              void* d_out, int out_size, void* d_ws, size_t ws_size,
                              hipStream_t stream) {
    const float* item  = (const float*)d_in[0];
    const float* query = (const float*)d_in[1];
    const float* Wq    = (const float*)d_in[2];
    const float* bq    = (const float*)d_in[3];
    const float* Wr    = (const float*)d_in[4];
    float* out = (float*)d_out;

    char* ws = (char*)d_ws;
    unsigned short* Bt = (unsigned short*)ws;                  // 8 MB
    float*          V  = (float*)(ws + (8 << 20));             // 1 MB

    k_trans_wq<<<dim3(512, 8), 256, 0, stream>>>(Wq, Bt);
    k_gemm_v  <<<1024,         256, 0, stream>>>(query, Bt, bq, Wr, V);
    k_score   <<<1024,         256, 0, stream>>>(item, V, out);
}

// Round 4
// 343.288 us; speedup vs baseline: 1.0774x; 1.0774x over previous
//
#include <hip/hip_runtime.h>

#define IDIM   256
#define HDIM   64
#define BATCH  1024
#define NITEMS 200
#define NCOLS  (IDIM * HDIM)   // 16384

typedef __bf16 bf16x8 __attribute__((ext_vector_type(8)));
typedef float  f32x4  __attribute__((ext_vector_type(4)));

__device__ __forceinline__ unsigned short f2bf(float f) {
    unsigned int u = __float_as_uint(f);
    u += 0x7FFFu + ((u >> 16) & 1u);   // round-to-nearest-even
    return (unsigned short)(u >> 16);
}

// fast tanh: 1 - 2/(e^{2x}+1); v_exp+v_rcp, saturates correctly (rcp(inf)=0)
__device__ __forceinline__ float fast_tanh(float x) {
    float e2 = __expf(2.0f * x);
    return 1.0f - 2.0f * __builtin_amdgcn_rcpf(e2 + 1.0f);
}

// ---- query f32 (1024x256) -> bf16, layout unchanged ----
__global__ __launch_bounds__(256) void k_conv_q(const float* __restrict__ q,
                                                unsigned short* __restrict__ Aq) {
    int idx = blockIdx.x * 256 + threadIdx.x;        // 65536 float4s
    float4 f = ((const float4*)q)[idx];
    ushort4 o;
    o.x = f2bf(f.x); o.y = f2bf(f.y); o.z = f2bf(f.z); o.w = f2bf(f.w);
    ((ushort4*)Aq)[idx] = o;
}

// ---- W_q f32 (k=256 x n=16384) -> Bt bf16 [n][k] (transposed) ----
__global__ __launch_bounds__(256) void k_trans_wq(const float* __restrict__ Wq,
                                                  unsigned short* __restrict__ Bt) {
    __shared__ float tile[32][33];
    int n0 = blockIdx.x * 32;          // 512 n-tiles
    int k0 = blockIdx.y * 32;          // 8 k-tiles
    int tx = threadIdx.x & 31;
    int ty = threadIdx.x >> 5;         // 0..7
#pragma unroll
    for (int j = 0; j < 32; j += 8)
        tile[ty + j][tx] = Wq[(size_t)(k0 + ty + j) * NCOLS + n0 + tx];
    __syncthreads();
#pragma unroll
    for (int j = 0; j < 32; j += 8)
        Bt[(size_t)(n0 + ty + j) * IDIM + k0 + tx] = f2bf(tile[tx][ty + j]);
}

// ---- GEMM: P = Aq(1024x256) @ Wq(256x16384), fused bias+tanh+W_r reduce ->
//      V[b][i] = sum_h tanh(P[b, i*64+h] + b_q) * W_r[h]   (V: 1024x256 f32)
// One wave computes a 64(m) x 64(n) C tile == all 64 h for one i, 64 batches.
__global__ __launch_bounds__(256) void k_gemm_v(const unsigned short* __restrict__ Aq,
                                                const unsigned short* __restrict__ Bt,
                                                const float* __restrict__ bq,
                                                const float* __restrict__ Wr,
                                                float* __restrict__ V) {
    int w    = threadIdx.x >> 6;
    int lane = threadIdx.x & 63;
    int l16  = lane & 15;
    int quad = lane >> 4;
    int blk  = blockIdx.x;             // 1024 blocks
    int bn   = blk & 127;              // 128 n-blocks (each 2 n-tiles)
    int bm   = blk >> 7;               // 8 m-blocks  (each 2 m-tiles)
    int m_tile = bm * 2 + (w & 1);     // 0..15
    int n_tile = bn * 2 + (w >> 1);    // 0..255
    int m_base = m_tile * 64;
    int n_base = n_tile * 64;

    f32x4 acc[4][4] = {};
    const unsigned short* Ap = Aq + (size_t)(m_base + l16) * IDIM + quad * 8;
    const unsigned short* Bp = Bt + (size_t)(n_base + l16) * IDIM + quad * 8;

    // epilogue operands loaded early (L2-hot, independent of the K-loop)
    float bv[4], wr[4];
#pragma unroll
    for (int nt = 0; nt < 4; nt++) {
        int nl = nt * 16 + l16;
        bv[nt] = bq[n_base + nl];
        wr[nt] = Wr[nl];
    }

#pragma unroll
    for (int k0 = 0; k0 < IDIM; k0 += 32) {
        bf16x8 a[4], b[4];
#pragma unroll
        for (int t = 0; t < 4; t++) a[t] = *(const bf16x8*)(Ap + (size_t)t * 16 * IDIM + k0);
#pragma unroll
        for (int t = 0; t < 4; t++) b[t] = *(const bf16x8*)(Bp + (size_t)t * 16 * IDIM + k0);
#pragma unroll
        for (int mt = 0; mt < 4; mt++)
#pragma unroll
            for (int nt = 0; nt < 4; nt++)
                acc[mt][nt] = __builtin_amdgcn_mfma_f32_16x16x32_bf16(a[mt], b[nt], acc[mt][nt], 0, 0, 0);
    }

    int i = n_tile;
#pragma unroll
    for (int mt = 0; mt < 4; mt++) {
#pragma unroll
        for (int reg = 0; reg < 4; reg++) {
            float s = 0.0f;
#pragma unroll
            for (int nt = 0; nt < 4; nt++) {
                float c = acc[mt][nt][reg] + bv[nt];
                s += fast_tanh(c) * wr[nt];
            }
            // reduce over the 16 lanes (l16) of this quad-row group
            s += __shfl_xor(s, 1);
            s += __shfl_xor(s, 2);
            s += __shfl_xor(s, 4);
            s += __shfl_xor(s, 8);
            if (l16 == 0) {
                int m = m_base + mt * 16 + quad * 4 + reg;   // D row = quad*4+reg
                V[m * IDIM + i] = s;
            }
        }
    }
}

// ---- fused score -> exp -> weighted accumulate, single pass over item ----
// one item per quad (16 lanes), 2 in flight per quad, 8 per wave.
__global__ __launch_bounds__(256) void k_score(const float* __restrict__ item,
                                               const float* __restrict__ V,
                                               float* __restrict__ out) {
    __shared__ float lacc[16][IDIM];   // 16 KB partials
    __shared__ float lS[16];
    int b    = blockIdx.x;
    int tid  = threadIdx.x;
    int wid  = tid >> 6;
    int lane = tid & 63;
    int l16  = lane & 15;
    int quad = lane >> 4;

    const float4* itemB = (const float4*)(item + (size_t)b * NITEMS * IDIM);
    const float4* Vb    = (const float4*)(V + (size_t)b * IDIM);

    float4 v[4];
#pragma unroll
    for (int c = 0; c < 4; c++) v[c] = Vb[l16 + 16 * c];

    float4 acc[4];
#pragma unroll
    for (int c = 0; c < 4; c++) acc[c] = make_float4(0.f, 0.f, 0.f, 0.f);
    float S = 0.f;

    for (int chunk = wid; chunk < 25; chunk += 4) {
        int r0 = chunk * 8 + quad;       // item for x0
        int r1 = r0 + 4;                 // item for x1 (max 199)
        float4 x0[4], x1[4];
#pragma unroll
        for (int c = 0; c < 4; c++) x0[c] = itemB[(size_t)r0 * 64 + l16 + 16 * c];
#pragma unroll
        for (int c = 0; c < 4; c++) x1[c] = itemB[(size_t)r1 * 64 + l16 + 16 * c];

        float d0 = 0.f, d1 = 0.f;
#pragma unroll
        for (int c = 0; c < 4; c++) {
            d0 += x0[c].x * v[c].x + x0[c].y * v[c].y + x0[c].z * v[c].z + x0[c].w * v[c].w;
            d1 += x1[c].x * v[c].x + x1[c].y * v[c].y + x1[c].z * v[c].z + x1[c].w * v[c].w;
        }
#pragma unroll
        for (int m = 1; m < 16; m <<= 1) {
            d0 += __shfl_xor(d0, m);
            d1 += __shfl_xor(d1, m);
        }
        float e0 = __expf(d0);
        float e1 = __expf(d1);
        S += e0 + e1;
#pragma unroll
        for (int c = 0; c < 4; c++) {
            acc[c].x += e0 * x0[c].x + e1 * x1[c].x;
            acc[c].y += e0 * x0[c].y + e1 * x1[c].y;
            acc[c].z += e0 * x0[c].z + e1 * x1[c].z;
            acc[c].w += e0 * x0[c].w + e1 * x1[c].w;
        }
    }

    int row = wid * 4 + quad;            // 16 partial rows
#pragma unroll
    for (int c = 0; c < 4; c++)
        ((float4*)&lacc[row][0])[l16 + 16 * c] = acc[c];
    if (l16 == 0) lS[row] = S;
    __syncthreads();

    float s = 0.f;
#pragma unroll
    for (int i = 0; i < 16; i++) s += lacc[i][tid];
    float Stot = 0.f;
#pragma unroll
    for (int i = 0; i < 16; i++) Stot += lS[i];
    out[(size_t)b * IDIM + tid] = s / (1.0f + Stot);
}

extern "C" void kernel_launch(void* const* d_in, const int* in_sizes, int n_in,
                              void* d_out, int out_size, void* d_ws, size_t ws_size,
                              hipStream_t stream) {
    const float* item  = (const float*)d_in[0];
    const float* query = (const float*)d_in[1];
    const float* Wq    = (const float*)d_in[2];
    const float* bq    = (const float*)d_in[3];
    const float* Wr    = (const float*)d_in[4];
    float* out = (float*)d_out;

    char* ws = (char*)d_ws;
    unsigned short* Aq = (unsigned short*)ws;                          // 512 KB
    unsigned short* Bt = (unsigned short*)(ws + (512 << 10));          // 8 MB
    float*          V  = (float*)(ws + (512 << 10) + (8 << 20));       // 1 MB

    k_conv_q  <<<256,             256, 0, stream>>>(query, Aq);
    k_trans_wq<<<dim3(512, 8),    256, 0, stream>>>(Wq, Bt);
    k_gemm_v  <<<1024,            256, 0, stream>>>(Aq, Bt, bq, Wr, V);
    k_score   <<<1024,            256, 0, stream>>>(item, V, out);
}